// Round 1
// baseline (770.667 us; speedup 1.0000x reference)
//
#include <hip/hip_runtime.h>
#include <math.h>

#define NN 50000
#define NE 800000
#define INF_ 128
#define HIDD 64
#define NHEAD 4
#define NEG 0.2f

// ---------------- GEMM: out[N,256] = feat[N,128] @ W[128,256] + b ----------------
__global__ __launch_bounds__(256) void gemm_proj(
    const float* __restrict__ feat, const float* __restrict__ W,
    const float* __restrict__ b, float* __restrict__ out, int n_rows)
{
    __shared__ float lds[64 * 128];
    const int row0 = blockIdx.x * 64;
    const int tid = threadIdx.x;
    for (int i = tid; i < 64 * 128; i += 256) {
        int r = row0 + (i >> 7);
        lds[i] = (r < n_rows) ? feat[row0 * 128 + i] : 0.0f;
    }
    __syncthreads();
    const int col = tid;  // 0..255
    float acc[64];
#pragma unroll
    for (int r = 0; r < 64; ++r) acc[r] = 0.0f;
    for (int k = 0; k < 128; k += 4) {
        float w0 = W[(k + 0) * 256 + col];
        float w1 = W[(k + 1) * 256 + col];
        float w2 = W[(k + 2) * 256 + col];
        float w3 = W[(k + 3) * 256 + col];
#pragma unroll
        for (int r = 0; r < 64; ++r) {
            const float4 f = *reinterpret_cast<const float4*>(&lds[(r << 7) + k]);
            acc[r] = fmaf(f.x, w0, acc[r]);
            acc[r] = fmaf(f.y, w1, acc[r]);
            acc[r] = fmaf(f.z, w2, acc[r]);
            acc[r] = fmaf(f.w, w3, acc[r]);
        }
    }
    const float bias = b[col];
#pragma unroll
    for (int r = 0; r < 64; ++r) {
        int row = row0 + r;
        if (row < n_rows) out[row * 256 + col] = acc[r] + bias;
    }
}

// ---------------- CSR build ----------------
__global__ void count_deg(const int* __restrict__ dst, int* __restrict__ deg)
{
    int e = blockIdx.x * blockDim.x + threadIdx.x;
    if (e < NE) atomicAdd(&deg[dst[e]], 1);
}

__global__ __launch_bounds__(1024) void scan_deg(const int* __restrict__ deg,
                                                 int* __restrict__ row_start)
{
    __shared__ int part[1024];
    const int tid = threadIdx.x;
    const int CH = (NN + 1023) / 1024;  // 49
    int begin = tid * CH;
    int end_ = begin + CH; if (end_ > NN) end_ = NN;
    int s = 0;
    for (int i = begin; i < end_; ++i) s += deg[i];
    part[tid] = s;
    __syncthreads();
    for (int off = 1; off < 1024; off <<= 1) {
        int v = (tid >= off) ? part[tid - off] : 0;
        __syncthreads();
        part[tid] += v;
        __syncthreads();
    }
    int base = (tid > 0) ? part[tid - 1] : 0;
    for (int i = begin; i < end_; ++i) {
        row_start[i] = base;
        base += deg[i];
    }
    if (tid == 1023) row_start[NN] = part[1023];
}

__global__ void scatter_edges(const int* __restrict__ dst,
                              const int* __restrict__ row_start,
                              int* __restrict__ cursor, int* __restrict__ edge_list)
{
    int e = blockIdx.x * blockDim.x + threadIdx.x;
    if (e < NE) {
        int d = dst[e];
        int pos = atomicAdd(&cursor[d], 1);
        edge_list[row_start[d] + pos] = e;
    }
}

// ---------------- Layer-1 edge kernel: block = node, wave = head ----------------
__global__ __launch_bounds__(256) void edge_layer1(
    const float* __restrict__ hs, const float* __restrict__ hd,
    const float* __restrict__ attn, const int* __restrict__ src,
    const int* __restrict__ row_start, const int* __restrict__ edge_list,
    float* __restrict__ h1out)
{
    const int n = blockIdx.x;
    const int wid = threadIdx.x >> 6;   // head
    const int lane = threadIdx.x & 63;  // feature dim
    const int fi = wid * 64 + lane;
    const float hdv = hd[n * 256 + fi];
    const float av = attn[fi];
    const int beg = row_start[n];
    const int end_ = row_start[n + 1];
    float m = -INFINITY, den = 0.0f, acc = 0.0f;
    for (int i = beg; i < end_; ++i) {
        int e = edge_list[i];
        int s = src[e];
        float x = hs[s * 256 + fi];
        float t = x + hdv;
        t = (t > 0.0f) ? t : NEG * t;
        float p = t * av;
#pragma unroll
        for (int off = 32; off; off >>= 1) p += __shfl_xor(p, off, 64);
        float mn = fmaxf(m, p);
        float corr = expf(m - mn);  // first iter: exp(-inf)=0
        float w = expf(p - mn);
        den = den * corr + w;
        acc = acc * corr + w * x;
        m = mn;
    }
    float o = (den > 0.0f) ? acc / den : 0.0f;
    o = (o > 0.0f) ? o : (expf(o) - 1.0f);  // ELU
    h1out[n * 256 + fi] = o;
}

// ---------------- Layer-2 projections: wave per node ----------------
__global__ __launch_bounds__(256) void gemv2(
    const float* __restrict__ h1,
    const float* __restrict__ W2s, const float* __restrict__ b2s,
    const float* __restrict__ W2d, const float* __restrict__ b2d,
    float* __restrict__ hs2, float* __restrict__ hd2)
{
    const int n = blockIdx.x * 4 + (threadIdx.x >> 6);
    const int lane = threadIdx.x & 63;
    if (n >= NN) return;
    const float4 x = *reinterpret_cast<const float4*>(&h1[n * 256 + lane * 4]);
    float xv[4] = {x.x, x.y, x.z, x.w};
    float s0 = 0, s1 = 0, d0 = 0, d1 = 0;
#pragma unroll
    for (int j = 0; j < 4; ++j) {
        int k = lane * 4 + j;
        s0 = fmaf(xv[j], W2s[k * 2 + 0], s0);
        s1 = fmaf(xv[j], W2s[k * 2 + 1], s1);
        d0 = fmaf(xv[j], W2d[k * 2 + 0], d0);
        d1 = fmaf(xv[j], W2d[k * 2 + 1], d1);
    }
#pragma unroll
    for (int off = 32; off; off >>= 1) {
        s0 += __shfl_xor(s0, off, 64);
        s1 += __shfl_xor(s1, off, 64);
        d0 += __shfl_xor(d0, off, 64);
        d1 += __shfl_xor(d1, off, 64);
    }
    if (lane == 0) {
        hs2[n * 2 + 0] = s0 + b2s[0];
        hs2[n * 2 + 1] = s1 + b2s[1];
        hd2[n * 2 + 0] = d0 + b2d[0];
        hd2[n * 2 + 1] = d1 + b2d[1];
    }
}

// ---------------- Layer-2 edge kernel: thread per node ----------------
__global__ void edge_layer2(
    const float* __restrict__ hs2, const float* __restrict__ hd2,
    const float* __restrict__ attn2, const int* __restrict__ src,
    const int* __restrict__ row_start, const int* __restrict__ edge_list,
    float* __restrict__ out)
{
    int n = blockIdx.x * blockDim.x + threadIdx.x;
    if (n >= NN) return;
    const float a0 = attn2[0], a1 = attn2[1];
    const float hd0 = hd2[n * 2], hd1 = hd2[n * 2 + 1];
    const int beg = row_start[n], end_ = row_start[n + 1];
    float m = -INFINITY, den = 0.0f, acc0 = 0.0f, acc1 = 0.0f;
    for (int i = beg; i < end_; ++i) {
        int e = edge_list[i];
        int s = src[e];
        float x0 = hs2[s * 2], x1 = hs2[s * 2 + 1];
        float t0 = x0 + hd0; t0 = (t0 > 0.0f) ? t0 : NEG * t0;
        float t1 = x1 + hd1; t1 = (t1 > 0.0f) ? t1 : NEG * t1;
        float p = fmaf(t0, a0, t1 * a1);
        float mn = fmaxf(m, p);
        float corr = expf(m - mn);
        float w = expf(p - mn);
        den = den * corr + w;
        acc0 = acc0 * corr + w * x0;
        acc1 = acc1 * corr + w * x1;
        m = mn;
    }
    if (den > 0.0f) {
        out[n * 2 + 0] = acc0 / den;
        out[n * 2 + 1] = acc1 / den;
    } else {
        out[n * 2 + 0] = 0.0f;
        out[n * 2 + 1] = 0.0f;
    }
}

// ---------------- launch ----------------
extern "C" void kernel_launch(void* const* d_in, const int* in_sizes, int n_in,
                              void* d_out, int out_size, void* d_ws, size_t ws_size,
                              hipStream_t stream)
{
    const float* feat  = (const float*)d_in[0];
    const int*   src   = (const int*)d_in[1];
    const int*   dst   = (const int*)d_in[2];
    const float* W1s   = (const float*)d_in[3];
    const float* b1s   = (const float*)d_in[4];
    const float* W1d   = (const float*)d_in[5];
    const float* b1d   = (const float*)d_in[6];
    const float* attn1 = (const float*)d_in[7];
    const float* W2s   = (const float*)d_in[8];
    const float* b2s   = (const float*)d_in[9];
    const float* W2d   = (const float*)d_in[10];
    const float* b2d   = (const float*)d_in[11];
    const float* attn2 = (const float*)d_in[12];
    float* out = (float*)d_out;

    // workspace layout (all 256B-aligned)
    char* ws = (char*)d_ws;
    size_t off = 0;
    auto alloc = [&](size_t bytes) {
        char* p = ws + off;
        off += (bytes + 255) & ~size_t(255);
        return p;
    };
    float* hs1       = (float*)alloc((size_t)NN * 256 * 4);
    float* hd1       = (float*)alloc((size_t)NN * 256 * 4);
    float* h1        = (float*)alloc((size_t)NN * 256 * 4);
    int*   edge_list = (int*)alloc((size_t)NE * 4);
    int*   row_start = (int*)alloc((size_t)(NN + 1) * 4);
    int*   deg       = (int*)alloc((size_t)NN * 4);
    int*   cursor    = (int*)alloc((size_t)NN * 4);
    float* hs2       = (float*)alloc((size_t)NN * 2 * 4);
    float* hd2       = (float*)alloc((size_t)NN * 2 * 4);
    (void)ws_size; (void)n_in; (void)in_sizes; (void)out_size;

    hipMemsetAsync(deg, 0, (size_t)NN * 4, stream);
    hipMemsetAsync(cursor, 0, (size_t)NN * 4, stream);

    const int gemm_blocks = (NN + 63) / 64;  // 782
    gemm_proj<<<gemm_blocks, 256, 0, stream>>>(feat, W1s, b1s, hs1, NN);
    gemm_proj<<<gemm_blocks, 256, 0, stream>>>(feat, W1d, b1d, hd1, NN);

    const int eb = (NE + 255) / 256;  // 3125
    count_deg<<<eb, 256, 0, stream>>>(dst, deg);
    scan_deg<<<1, 1024, 0, stream>>>(deg, row_start);
    scatter_edges<<<eb, 256, 0, stream>>>(dst, row_start, cursor, edge_list);

    edge_layer1<<<NN, 256, 0, stream>>>(hs1, hd1, attn1, src, row_start, edge_list, h1);

    gemv2<<<(NN + 3) / 4, 256, 0, stream>>>(h1, W2s, b2s, W2d, b2d, hs2, hd2);

    edge_layer2<<<(NN + 255) / 256, 256, 0, stream>>>(hs2, hd2, attn2, src,
                                                      row_start, edge_list, out);
}